// Round 26
// baseline (398.941 us; speedup 1.0000x reference)
//
#include <hip/hip_runtime.h>

#define NODE_DIM 256
#define HIDDEN 64
#define NUM_REL 10

#define FMA4(A, S, W) do { \
    (A).x = fmaf((S), (W).x, (A).x); \
    (A).y = fmaf((S), (W).y, (A).y); \
    (A).z = fmaf((S), (W).z, (A).z); \
    (A).w = fmaf((S), (W).w, (A).w); } while (0)

#define ELEM(V, I) ((I) == 0 ? (V).x : (I) == 1 ? (V).y : (I) == 2 ? (V).z : (V).w)

// Edge kernel: SEQUENTIAL J-HALF SPLIT over a persistent per-thread LDS
// scratch. Rationale (R17-R25): the allocator insists on a 56-VGPR form; the
// one-shot 64-accumulator version demands ~110 -> AGPR shuttle (~50us extra
// VALU). This version's peak demand is ~54 regs (8 float4 accs + lg[10]),
// which FITS the 56-reg attractor -> nothing to shuttle (R10 showed the
// half-split form gets VGPR 44, shuttle-free; its 499us came from streaming
// Hc twice from GLOBAL — here the restage hits L2, FETCH unchanged).
// Chain order per output element unchanged: k ascending over W3 rows
// 64..127, +b3 after, relu, j-ascending logits (half 0 then half 1), +b4
// -> bit-identical to np.
__global__ __launch_bounds__(256, 4) void edge_kernel(
    const int* __restrict__ ei,
    const float* __restrict__ H, const float* __restrict__ A,
    const float* __restrict__ W3, const float* __restrict__ b3,
    const float* __restrict__ W4, const float* __restrict__ b4,
    float* __restrict__ out_type, float* __restrict__ out_probs, int E)
{
    __shared__ float4 HcS[256 * 8];   // 32 KB: per-thread 8-quad scratch

    const int tid = threadIdx.x;
    const int e = blockIdx.x * 256 + tid;
    const bool valid = (e < E);
    const int sw = tid & 7;
    float4* myscr = &HcS[tid * 8];

    const int c = valid ? ei[E + e] : 0;
    const int r = valid ? ei[e] : 0;
    const float4* src = (const float4*)(H + (size_t)c * 64);
    const float4* Ar  = (const float4*)(A + (size_t)r * 64);

    const float* W3b = W3 + 64 * 64;

    float lg[NUM_REL];
    #pragma unroll
    for (int j = 0; j < NUM_REL; ++j) lg[j] = 0.0f;

    // stage chunk 0 (Hc quads 0..7) for half 0
    #pragma unroll
    for (int q = 0; q < 8; ++q) myscr[q ^ sw] = src[q];

    #pragma unroll
    for (int half = 0; half < 2; ++half) {       // fully unrolled: static code
        if (half == 1) {
            // restage chunk 0 (lines are L2-hot from half 0 -> no HBM refetch)
            #pragma unroll
            for (int q = 0; q < 8; ++q) myscr[q ^ sw] = src[q];
        }

        // seed this half's 8 acc quads from the A chain prefix
        float4 acc[8];
        #pragma unroll
        for (int j = 0; j < 8; ++j) acc[j] = Ar[half * 8 + j];

        // k4 = 0..7 from chunk 0 (k ascending; this half's 32-col W slice)
        #pragma unroll 1
        for (int k4 = 0; k4 < 8; ++k4) {
            const float4 hv = myscr[k4 ^ sw];
            #pragma unroll
            for (int i = 0; i < 4; ++i) {
                const float s = ELEM(hv, i);
                const float* w = W3b + (size_t)(k4 * 4 + i) * 64 + half * 32;
                #pragma unroll
                for (int j = 0; j < 8; ++j) {
                    float4 wv = *(const float4*)(w + 4 * j);
                    FMA4(acc[j], s, wv);
                }
            }
        }

        // restage chunk 1 (Hc quads 8..15; L2-hot on half 1)
        #pragma unroll
        for (int q = 0; q < 8; ++q) myscr[q ^ sw] = src[8 + q];

        // k4 = 8..15 from chunk 1
        #pragma unroll 1
        for (int k4 = 8; k4 < 16; ++k4) {
            const float4 hv = myscr[(k4 - 8) ^ sw];
            #pragma unroll
            for (int i = 0; i < 4; ++i) {
                const float s = ELEM(hv, i);
                const float* w = W3b + (size_t)(k4 * 4 + i) * 64 + half * 32;
                #pragma unroll
                for (int j = 0; j < 8; ++j) {
                    float4 wv = *(const float4*)(w + 4 * j);
                    FMA4(acc[j], s, wv);
                }
            }
        }

        // + b3 (this half's slice), relu — j ascending
        #pragma unroll
        for (int j = 0; j < 8; ++j) {
            float4 bv = *(const float4*)(b3 + half * 32 + 4 * j);
            acc[j].x = fmaxf(acc[j].x + bv.x, 0.f);
            acc[j].y = fmaxf(acc[j].y + bv.y, 0.f);
            acc[j].z = fmaxf(acc[j].z + bv.z, 0.f);
            acc[j].w = fmaxf(acc[j].w + bv.w, 0.f);
        }

        // logits: continue the lg chain over this half's j-range, ascending
        #pragma unroll
        for (int jq = 0; jq < 8; ++jq) {
            #pragma unroll
            for (int i = 0; i < 4; ++i) {
                const float s = ELEM(acc[jq], i);
                const float* w = W4 + (size_t)(half * 32 + jq * 4 + i) * NUM_REL;
                #pragma unroll
                for (int j = 0; j < NUM_REL; ++j) lg[j] = fmaf(s, w[j], lg[j]);
            }
        }
    }

    if (!valid) return;

    #pragma unroll
    for (int j = 0; j < NUM_REL; ++j) lg[j] += b4[j];

    // argmax, first occurrence
    int best = 0;
    float bm = lg[0];
    #pragma unroll
    for (int j = 1; j < NUM_REL; ++j)
        if (lg[j] > bm) { bm = lg[j]; best = j; }

    // softmax fp32
    float p[NUM_REL];
    float sum = 0.0f;
    #pragma unroll
    for (int j = 0; j < NUM_REL; ++j) {
        p[j] = expf(lg[j] - bm);
        sum += p[j];
    }
    float inv = 1.0f / sum;

    out_type[e] = (float)best;
    float* op = out_probs + (size_t)e * NUM_REL;
    #pragma unroll
    for (int j = 0; j < NUM_REL; ++j) op[j] = p[j] * inv;
}

// Node pipeline: R25 verbatim (~94 us). Block = 4 waves x 64 lanes; lane =
// node, wave = j-slice via inline-asm v_readfirstlane -> SGPR -> s_load
// weights. h1/h via LDS [64][65]. Per-element np/BLAS chain: acc=0, k
// ascending fmaf over FULL K, bias AFTER, relu -> bit-identical.
__global__ __launch_bounds__(256, 4) void node_kernel(
    const float* __restrict__ x,
    const float* __restrict__ W1, const float* __restrict__ b1,
    const float* __restrict__ W2, const float* __restrict__ b2,
    const float* __restrict__ W3,
    float* __restrict__ Hout, float* __restrict__ Aout, int N)
{
    __shared__ float h1s[64][65];
    __shared__ float hs[64][65];

    const int tid  = threadIdx.x;
    const int lane = tid & 63;
    int jb;
    asm("v_readfirstlane_b32 %0, %1" : "=s"(jb) : "v"((tid >> 6) << 4));
    const int n    = blockIdx.x * 64 + lane;
    const bool valid = (n < N);
    const int nc   = valid ? n : (N - 1);

    // ---- L1 slice: h1[jb..jb+16) = relu((x@W1) + b1) ----
    float4 a0 = make_float4(0.f, 0.f, 0.f, 0.f);
    float4 a1 = a0, a2 = a0, a3 = a0;

    const float4* xr = (const float4*)(x + (size_t)nc * NODE_DIM);
    #pragma unroll 1
    for (int k4 = 0; k4 < NODE_DIM / 4; ++k4) {
        float4 xv = xr[k4];
        #pragma unroll
        for (int i = 0; i < 4; ++i) {
            const float s = ELEM(xv, i);
            const float4* w = (const float4*)(W1 + (size_t)(k4 * 4 + i) * 64 + jb);
            float4 w0 = w[0], w1 = w[1], w2 = w[2], w3 = w[3];
            FMA4(a0, s, w0); FMA4(a1, s, w1);
            FMA4(a2, s, w2); FMA4(a3, s, w3);
        }
    }
    {
        const float4* bv = (const float4*)(b1 + jb);
        float4 b0 = bv[0], b1v = bv[1], b2v = bv[2], b3v = bv[3];
        float* d = &h1s[lane][jb];
        d[0]  = fmaxf(a0.x + b0.x, 0.f);  d[1]  = fmaxf(a0.y + b0.y, 0.f);
        d[2]  = fmaxf(a0.z + b0.z, 0.f);  d[3]  = fmaxf(a0.w + b0.w, 0.f);
        d[4]  = fmaxf(a1.x + b1v.x, 0.f); d[5]  = fmaxf(a1.y + b1v.y, 0.f);
        d[6]  = fmaxf(a1.z + b1v.z, 0.f); d[7]  = fmaxf(a1.w + b1v.w, 0.f);
        d[8]  = fmaxf(a2.x + b2v.x, 0.f); d[9]  = fmaxf(a2.y + b2v.y, 0.f);
        d[10] = fmaxf(a2.z + b2v.z, 0.f); d[11] = fmaxf(a2.w + b2v.w, 0.f);
        d[12] = fmaxf(a3.x + b3v.x, 0.f); d[13] = fmaxf(a3.y + b3v.y, 0.f);
        d[14] = fmaxf(a3.z + b3v.z, 0.f); d[15] = fmaxf(a3.w + b3v.w, 0.f);
    }
    __syncthreads();

    // ---- L2 slice: h[jb..jb+16) = (h1@W2) + b2 ----
    a0 = make_float4(0.f, 0.f, 0.f, 0.f); a1 = a0; a2 = a0; a3 = a0;
    #pragma unroll 1
    for (int k = 0; k < 64; ++k) {
        const float s = h1s[lane][k];
        const float4* w = (const float4*)(W2 + (size_t)k * 64 + jb);
        float4 w0 = w[0], w1 = w[1], w2 = w[2], w3 = w[3];
        FMA4(a0, s, w0); FMA4(a1, s, w1);
        FMA4(a2, s, w2); FMA4(a3, s, w3);
    }
    {
        const float4* bv = (const float4*)(b2 + jb);
        float4 b0 = bv[0], b1v = bv[1], b2v = bv[2], b3v = bv[3];
        float4 r0, r1, r2, r3;
        r0.x = a0.x + b0.x;  r0.y = a0.y + b0.y;  r0.z = a0.z + b0.z;  r0.w = a0.w + b0.w;
        r1.x = a1.x + b1v.x; r1.y = a1.y + b1v.y; r1.z = a1.z + b1v.z; r1.w = a1.w + b1v.w;
        r2.x = a2.x + b2v.x; r2.y = a2.y + b2v.y; r2.z = a2.z + b2v.z; r2.w = a2.w + b2v.w;
        r3.x = a3.x + b3v.x; r3.y = a3.y + b3v.y; r3.z = a3.z + b3v.z; r3.w = a3.w + b3v.w;
        float* d = &hs[lane][jb];
        d[0]  = r0.x; d[1]  = r0.y; d[2]  = r0.z; d[3]  = r0.w;
        d[4]  = r1.x; d[5]  = r1.y; d[6]  = r1.z; d[7]  = r1.w;
        d[8]  = r2.x; d[9]  = r2.y; d[10] = r2.z; d[11] = r2.w;
        d[12] = r3.x; d[13] = r3.y; d[14] = r3.z; d[15] = r3.w;
        if (valid) {
            float4* g = (float4*)(Hout + (size_t)n * 64 + jb);
            g[0] = r0; g[1] = r1; g[2] = r2; g[3] = r3;
        }
    }
    __syncthreads();

    // ---- L3 row-half partial slice: A[jb..jb+16) = h @ W3[0:64], no bias ----
    a0 = make_float4(0.f, 0.f, 0.f, 0.f); a1 = a0; a2 = a0; a3 = a0;
    #pragma unroll 1
    for (int k = 0; k < 64; ++k) {
        const float s = hs[lane][k];
        const float4* w = (const float4*)(W3 + (size_t)k * 64 + jb);
        float4 w0 = w[0], w1 = w[1], w2 = w[2], w3 = w[3];
        FMA4(a0, s, w0); FMA4(a1, s, w1);
        FMA4(a2, s, w2); FMA4(a3, s, w3);
    }
    if (valid) {
        float4* g = (float4*)(Aout + (size_t)n * 64 + jb);
        g[0] = a0; g[1] = a1; g[2] = a2; g[3] = a3;
    }
}

extern "C" void kernel_launch(void* const* d_in, const int* in_sizes, int n_in,
                              void* d_out, int out_size, void* d_ws, size_t ws_size,
                              hipStream_t stream)
{
    const float* x  = (const float*)d_in[0];
    const int*   ei = (const int*)d_in[1];
    const float* W1 = (const float*)d_in[2];
    const float* b1 = (const float*)d_in[3];
    const float* W2 = (const float*)d_in[4];
    const float* b2 = (const float*)d_in[5];
    const float* W3 = (const float*)d_in[6];
    const float* b3 = (const float*)d_in[7];
    const float* W4 = (const float*)d_in[8];
    const float* b4 = (const float*)d_in[9];

    int N = in_sizes[0] / NODE_DIM;   // 100000
    int E = in_sizes[1] / 2;          // 1600000

    // ws: H [N*64] f32 | A [N*64] f32   (51.2 MB total)
    float* H = (float*)d_ws;
    float* A = H + (size_t)N * 64;

    int nb = (N + 63) / 64;
    int eb = (E + 255) / 256;

    float* out_type  = (float*)d_out;
    float* out_probs = (float*)d_out + E;

    hipLaunchKernelGGL(node_kernel, dim3(nb), dim3(256), 0, stream,
                       x, W1, b1, W2, b2, W3, H, A, N);
    hipLaunchKernelGGL(edge_kernel, dim3(eb), dim3(256), 0, stream,
                       ei, H, A, W3, b3, W4, b4, out_type, out_probs, E);
}